// Round 6
// baseline (267.315 us; speedup 1.0000x reference)
//
#include <hip/hip_runtime.h>
#include <stdint.h>

// ---------------------------------------------------------------------------
// TimeCondAttention on MI355X (gfx950)
// B=2, N=2048, DIM=512, H=8, DH=64, TIME_DIM=512
// R6: barrier-free occupancy-max k_attn:
//   - wave = 16 q-rows x 1024-key half; 4096 waves; __launch_bounds__(256,4)
//   - K/V read global->VGPR (L2-resident per XCD), bias reg ping-pong depth 1
//   - zero s_barrier / zero global_load_lds / compiler-managed waitcnts
//   - partial (acc,m,l) to f32 workspace; k_comb merges halves -> ah/al
// ---------------------------------------------------------------------------

using s16x8 = __attribute__((ext_vector_type(8))) short;
using f32x4 = __attribute__((ext_vector_type(4))) float;
using u16x4 = __attribute__((ext_vector_type(4))) unsigned short;

#define EPSV 1e-5f
#define NEGV 1e6f

__device__ __forceinline__ unsigned short f2bf(float f) {
    unsigned int u = __float_as_uint(f);
    u += 0x7FFFu + ((u >> 16) & 1u);   // RNE (inputs finite)
    return (unsigned short)(u >> 16);
}
__device__ __forceinline__ float bf2f(unsigned short s) {
    return __uint_as_float((unsigned int)s << 16);
}

__device__ __forceinline__ void gl_lds16(const void* g, void* l) {
    __builtin_amdgcn_global_load_lds((const __attribute__((address_space(1))) void*)g,
                                     (__attribute__((address_space(3))) void*)l, 16, 0, 0);
}

__device__ __forceinline__ f32x4 mfma_bf16(s16x8 a, s16x8 b, f32x4 c) {
    return __builtin_amdgcn_mfma_f32_16x16x32_bf16(a, b, c, 0, 0, 0);
}

// ---------------- K0: weight conversion (w_q, w_kv bf16; w_out hi/lo split) --
__global__ void k_prep(const float* __restrict__ w_q, const float* __restrict__ w_kv,
                       const float* __restrict__ w_out,
                       unsigned short* __restrict__ wq, unsigned short* __restrict__ wkv,
                       unsigned short* __restrict__ wo_h, unsigned short* __restrict__ wo_l) {
    int idx = blockIdx.x * 256 + threadIdx.x;         // total 1,048,576 exactly
    if (idx < 262144) {
        wq[idx] = f2bf(w_q[idx]);
    } else if (idx < 786432) {
        int i = idx - 262144;
        wkv[i] = f2bf(w_kv[i]);
    } else {
        int i = idx - 786432;
        float v = w_out[i];
        unsigned short h = f2bf(v);
        wo_h[i] = h;
        wo_l[i] = f2bf(v - bf2f(h));
    }
}

// ---------------- K1: t = silu(time) @ w_time.T + b_time  ([2][1024] f32) ----
__global__ void k_time(const float* __restrict__ timev, const float* __restrict__ w_time,
                       const float* __restrict__ b_time, float* __restrict__ tc) {
    int wid = threadIdx.x >> 6, lane = threadIdx.x & 63;
    int b = blockIdx.x >> 8;
    int j = (blockIdx.x & 255) * 4 + wid;             // 0..1023
    const float* tv = timev + b * 512;
    const float* wr = w_time + (size_t)j * 512;
    float acc = 0.f;
#pragma unroll
    for (int i = 0; i < 8; ++i) {
        int k = i * 64 + lane;
        float t = tv[k];
        float s = t / (1.f + __expf(-t));             // silu
        acc += s * wr[k];
    }
#pragma unroll
    for (int m = 32; m >= 1; m >>= 1) acc += __shfl_xor(acc, m);
    if (lane == 0) tc[b * 1024 + j] = acc + b_time[j];
}

// ---------------- K2: LayerNorm + FiLM + seq_mask -> xn(bf16); x -> bf16 -----
__global__ void k_lnfilm(const float* __restrict__ x, const float* __restrict__ gamma,
                         const float* __restrict__ seq_mask, const float* __restrict__ tc,
                         unsigned short* __restrict__ xbf, unsigned short* __restrict__ xnbf) {
    int row = blockIdx.x;                             // b*2048 + n
    int b = row >> 11;
    int tid = threadIdx.x, wid = tid >> 6, lane = tid & 63;
    float2 xv = *(const float2*)(x + (size_t)row * 512 + tid * 2);
    float s = xv.x + xv.y;
    float sq = xv.x * xv.x + xv.y * xv.y;
#pragma unroll
    for (int m = 32; m >= 1; m >>= 1) { s += __shfl_xor(s, m); sq += __shfl_xor(sq, m); }
    __shared__ float red[8];
    if (lane == 0) { red[wid] = s; red[wid + 4] = sq; }
    __syncthreads();
    float ts = red[0] + red[1] + red[2] + red[3];
    float tq = red[4] + red[5] + red[6] + red[7];
    float mu = ts * (1.f / 512.f);
    float var = tq * (1.f / 512.f) - mu * mu;
    float rs = rsqrtf(var + EPSV);
    float qm = seq_mask[row];
    int j = tid * 2;
    const float* scb = tc + b * 1024;
    float o0 = ((xv.x - mu) * rs * gamma[j])     * (scb[j] + 1.f)     + scb[j + 512];
    float o1 = ((xv.y - mu) * rs * gamma[j + 1]) * (scb[j + 1] + 1.f) + scb[j + 513];
    size_t base = (size_t)row * 512 + j;
    xnbf[base]     = f2bf(o0 * qm);
    xnbf[base + 1] = f2bf(o1 * qm);
    xbf[base]      = f2bf(xv.x);
    xbf[base + 1]  = f2bf(xv.y);
}

// ---------------- K3: bf16 GEMM C = A[M,512] * W[Nout,512]^T, scatter epi ----
// EPI 0: q-proj (scale 0.125, [b,h,n,d]); EPI 1: kv-proj (k: [b,h,n,d], v: [b,h,d,n])
template<int EPI>
__launch_bounds__(256)
__global__ void k_gemm(const unsigned short* __restrict__ A, const unsigned short* __restrict__ W,
                       unsigned short* __restrict__ o0, unsigned short* __restrict__ o1) {
    __shared__ unsigned short a_t[128 * 64];
    __shared__ unsigned short b_t[128 * 64];
    int tid = threadIdx.x, lane = tid & 63, wid = tid >> 6;
    int lc = lane & 15, lq = lane >> 4;
    int wr = wid >> 1, wc = wid & 1;
    int m0 = blockIdx.x * 128, n0 = blockIdx.y * 128;
    f32x4 acc[4][4];
#pragma unroll
    for (int i = 0; i < 4; ++i)
#pragma unroll
        for (int jn = 0; jn < 4; ++jn)
#pragma unroll
            for (int e = 0; e < 4; ++e) acc[i][jn][e] = 0.f;
    const unsigned short* Ab = A + (size_t)m0 * 512;
    const unsigned short* Wb = W + (size_t)n0 * 512;
    int wbase = wid * 64;
    for (int kt = 0; kt < 8; ++kt) {
        __syncthreads();
        // stage 128x64 bf16 tiles; XOR-swizzled source so swizzled reads work
#pragma unroll
        for (int i = 0; i < 4; ++i) {
            int p = i * 256 + wbase + lane;
            int row = p >> 3, ls = (p & 7) ^ (row & 7);
            gl_lds16(Ab + (size_t)row * 512 + kt * 64 + ls * 8, a_t + (i * 256 + wbase) * 8);
            gl_lds16(Wb + (size_t)row * 512 + kt * 64 + ls * 8, b_t + (i * 256 + wbase) * 8);
        }
        __syncthreads();
        s16x8 af[4][2], bw[4][2];
        const char* ab = (const char*)a_t;
        const char* bb = (const char*)b_t;
#pragma unroll
        for (int mf = 0; mf < 4; ++mf) {
            int row = wr * 64 + mf * 16 + lc;
            int key = (row & 7) << 4;
            af[mf][0] = *(const s16x8*)(ab + row * 128 + ((lq * 16) ^ key));
            af[mf][1] = *(const s16x8*)(ab + row * 128 + ((64 + lq * 16) ^ key));
        }
#pragma unroll
        for (int nf = 0; nf < 4; ++nf) {
            int row = wc * 64 + nf * 16 + lc;
            int key = (row & 7) << 4;
            bw[nf][0] = *(const s16x8*)(bb + row * 128 + ((lq * 16) ^ key));
            bw[nf][1] = *(const s16x8*)(bb + row * 128 + ((64 + lq * 16) ^ key));
        }
#pragma unroll
        for (int mf = 0; mf < 4; ++mf)
#pragma unroll
            for (int nf = 0; nf < 4; ++nf) {
                acc[mf][nf] = mfma_bf16(af[mf][0], bw[nf][0], acc[mf][nf]);
                acc[mf][nf] = mfma_bf16(af[mf][1], bw[nf][1], acc[mf][nf]);
            }
    }
#pragma unroll
    for (int mf = 0; mf < 4; ++mf)
#pragma unroll
        for (int nf = 0; nf < 4; ++nf) {
            int grow0 = m0 + wr * 64 + mf * 16 + lq * 4;
            int gcol = n0 + wc * 64 + nf * 16 + lc;
            int b = grow0 >> 11, nb = grow0 & 2047;
            if (EPI == 0) {
                int h = gcol >> 6, d = gcol & 63;
#pragma unroll
                for (int r = 0; r < 4; ++r)
                    o0[((size_t)((b * 8 + h) * 2048 + nb + r)) * 64 + d] =
                        f2bf(acc[mf][nf][r] * 0.125f);
            } else if (gcol < 512) {
                int h = gcol >> 6, d = gcol & 63;
#pragma unroll
                for (int r = 0; r < 4; ++r)
                    o0[((size_t)((b * 8 + h) * 2048 + nb + r)) * 64 + d] = f2bf(acc[mf][nf][r]);
            } else {
                int jj = gcol & 511;
                int h = jj >> 6, d = jj & 63;
                u16x4 vv;
#pragma unroll
                for (int r = 0; r < 4; ++r) vv[r] = f2bf(acc[mf][nf][r]);
                // V stored transposed [b,h,d,n]; 4 consecutive n -> 8B store
                *(u16x4*)(o1 + ((size_t)((b * 8 + h) * 64 + d)) * 2048 + nb) = vv;
            }
        }
}

// ---------------- K4: barrier-free flash attention (key-split halves) -------
__launch_bounds__(256, 4)
__global__ void k_attn(const unsigned short* __restrict__ qg, const unsigned short* __restrict__ kg,
                       const unsigned short* __restrict__ vt, const float* __restrict__ bias,
                       const float* __restrict__ seq_mask,
                       float* __restrict__ po, float* __restrict__ ml) {
    __shared__ unsigned short p_lds[4][1024];   // 2KB per wave, wave-local only

    int tid = threadIdx.x, lane = tid & 63, w = tid >> 6;
    int lc = lane & 15, lq = lane >> 4;

    // XCD-contiguous mapping: 1024 blocks; XCD c -> bh {2c, 2c+1}
    int lin = blockIdx.x;
    int vid = (lin & 7) * 128 + (lin >> 3);
    int bh = vid >> 6;
    int slot = (vid & 63) * 4 + w;            // 0..255 per bh
    int half = slot & 1;
    int q0 = (slot >> 1) * 16;
    int b = bh >> 3, h = bh & 7;
    (void)h;

    // Q fragments (B-operand of swapped mfma)
    const unsigned short* qbase = qg + ((size_t)bh * 2048 + q0) * 64;
    s16x8 aq0 = *(const s16x8*)(qbase + lc * 64 + lq * 8);
    s16x8 aq1 = *(const s16x8*)(qbase + lc * 64 + 32 + lq * 8);

    const unsigned short* kb = kg + ((size_t)bh * 2048 + half * 1024) * 64;
    const unsigned short* vb = vt + (size_t)bh * 64 * 2048 + half * 1024;
    const float* bq = bias + ((size_t)bh * 2048 + q0 + lc) * 2048 + half * 1024;
    const float* sk = seq_mask + b * 2048 + half * 1024;
    float qm = seq_mask[b * 2048 + q0 + lc];

    char* pw = (char*)(&p_lds[w][0]);
    int swz = (lc & 7) << 4;

    float mst = -1e30f, lst = 0.f;
    f32x4 acc[4];
#pragma unroll
    for (int df = 0; df < 4; ++df)
#pragma unroll
        for (int e = 0; e < 4; ++e) acc[df][e] = 0.f;

    f32x4 brA[4], brB[4];
#pragma unroll
    for (int nf = 0; nf < 4; ++nf)
        brA[nf] = *(const f32x4*)(bq + nf * 16 + lq * 4);

    auto iter = [&](int kt, f32x4 (&cur)[4], f32x4 (&nxt)[4]) {
        // prefetch next bias tile (depth 1; compiler-managed wait on use)
        int bt = kt < 15 ? kt + 1 : 15;
#pragma unroll
        for (int nf = 0; nf < 4; ++nf)
            nxt[nf] = *(const f32x4*)(bq + bt * 64 + nf * 16 + lq * 4);

        // S^T = K Q^T : K fragments straight from global (L2-resident)
        const unsigned short* kkt = kb + kt * 64 * 64;
        f32x4 sv[4];
#pragma unroll
        for (int nf = 0; nf < 4; ++nf) {
            s16x8 k0 = *(const s16x8*)(kkt + (nf * 16 + lc) * 64 + lq * 8);
            s16x8 k1 = *(const s16x8*)(kkt + (nf * 16 + lc) * 64 + 32 + lq * 8);
            f32x4 z;
            z[0] = 0.f; z[1] = 0.f; z[2] = 0.f; z[3] = 0.f;
            z = mfma_bf16(k0, aq0, z);
            z = mfma_bf16(k1, aq1, z);
            sv[nf] = z;
        }

        // V^T fragments issued early (latency hides under softmax)
        const unsigned short* vkt = vb + kt * 64;
        s16x8 vv[4][2];
#pragma unroll
        for (int df = 0; df < 4; ++df)
#pragma unroll
            for (int ks = 0; ks < 2; ++ks)
                vv[df][ks] = *(const s16x8*)(vkt + (size_t)(df * 16 + lc) * 2048 +
                                             ks * 32 + lq * 8);

        // bias + mask
#pragma unroll
        for (int nf = 0; nf < 4; ++nf) {
            f32x4 km = *(const f32x4*)(sk + kt * 64 + nf * 16 + lq * 4);
            sv[nf] = sv[nf] + cur[nf] + (km * qm - 1.f) * NEGV;
        }

        // online softmax (row = q = lc; reduce over regs + 2 shfl)
        f32x4 m4 = sv[0];
#pragma unroll
        for (int nf = 1; nf < 4; ++nf)
#pragma unroll
            for (int e = 0; e < 4; ++e) m4[e] = fmaxf(m4[e], sv[nf][e]);
        float mx = fmaxf(fmaxf(m4[0], m4[1]), fmaxf(m4[2], m4[3]));
        mx = fmaxf(mx, __shfl_xor(mx, 16));
        mx = fmaxf(mx, __shfl_xor(mx, 32));
        float mn = fmaxf(mst, mx);
        float scl = __expf(mst - mn);
        mst = mn;
        float rsum = 0.f;
#pragma unroll
        for (int nf = 0; nf < 4; ++nf) {
            f32x4 p;
#pragma unroll
            for (int e = 0; e < 4; ++e) { p[e] = __expf(sv[nf][e] - mn); rsum += p[e]; }
            unsigned int w0 = ((unsigned)f2bf(p[1]) << 16) | f2bf(p[0]);
            unsigned int w1 = ((unsigned)f2bf(p[3]) << 16) | f2bf(p[2]);
            *(unsigned int*)(pw + lc * 128 + ((nf * 32 + lq * 8) ^ swz)) = w0;
            *(unsigned int*)(pw + lc * 128 + ((nf * 32 + lq * 8 + 4) ^ swz)) = w1;
        }
        rsum += __shfl_xor(rsum, 16);
        rsum += __shfl_xor(rsum, 32);
        lst = lst * scl + rsum;
#pragma unroll
        for (int df = 0; df < 4; ++df)
#pragma unroll
            for (int e = 0; e < 4; ++e) acc[df][e] *= scl;

        __builtin_amdgcn_sched_barrier(0);
        asm volatile("s_waitcnt lgkmcnt(0)");   // P visible (wave-local, in-order DS)
        __builtin_amdgcn_sched_barrier(0);      // rule #18

        s16x8 ap0 = *(const s16x8*)(pw + lc * 128 + ((lq * 16) ^ swz));
        s16x8 ap1 = *(const s16x8*)(pw + lc * 128 + ((64 + lq * 16) ^ swz));
#pragma unroll
        for (int df = 0; df < 4; ++df) {
            acc[df] = mfma_bf16(vv[df][0], ap0, acc[df]);
            acc[df] = mfma_bf16(vv[df][1], ap1, acc[df]);
        }
    };

    for (int t = 0; t < 8; ++t) {
        iter(2 * t, brA, brB);
        iter(2 * t + 1, brB, brA);
    }

    // partial output (unnormalized acc + m, l)
    float* prow = po + ((size_t)((half * 16 + bh) * 2048) + q0 + lc) * 64;
#pragma unroll
    for (int df = 0; df < 4; ++df)
        *(f32x4*)(prow + df * 16 + lq * 4) = acc[df];
    if (lq == 0) {
        int r = (half * 16 + bh) * 2048 + q0 + lc;
        ml[2 * r] = mst;
        ml[2 * r + 1] = lst;
    }
}

// ---------------- K4b: merge key-halves -> ah/al (hi/lo bf16 split) ---------
__global__ void k_comb(const float* __restrict__ po, const float* __restrict__ ml,
                       unsigned short* __restrict__ ah, unsigned short* __restrict__ al) {
    int g = blockIdx.x * 256 + threadIdx.x;   // 131072 = 32768 rows x 4 chunks
    int row = g >> 2, ch = g & 3;
    int bh = row >> 11, q = row & 2047;
    int b = bh >> 3, h = bh & 7;
    float m0 = ml[2 * row],           l0 = ml[2 * row + 1];
    float m1 = ml[2 * (row + 32768)], l1 = ml[2 * (row + 32768) + 1];
    float m = fmaxf(m0, m1);
    float e0 = __expf(m0 - m), e1 = __expf(m1 - m);
    float inv = 1.f / (e0 * l0 + e1 * l1);
    const float* p0 = po + (size_t)row * 64 + ch * 16;
    const float* p1 = p0 + (size_t)32768 * 64;
    size_t ob = ((size_t)(b * 2048 + q)) * 512 + h * 64 + ch * 16;
#pragma unroll
    for (int i = 0; i < 4; ++i) {
        f32x4 a0 = *(const f32x4*)(p0 + i * 4);
        f32x4 a1 = *(const f32x4*)(p1 + i * 4);
        u16x4 hi, lo;
#pragma unroll
        for (int e = 0; e < 4; ++e) {
            float o = (e0 * a0[e] + e1 * a1[e]) * inv;
            unsigned short hb = f2bf(o);
            hi[e] = hb;
            lo[e] = f2bf(o - bf2f(hb));
        }
        *(u16x4*)(ah + ob + i * 4) = hi;
        *(u16x4*)(al + ob + i * 4) = lo;
    }
}

// ---------------- K5: out = (Ah+Al)(Wh+Wl)^T * seq_mask  (3-term split) -----
__launch_bounds__(256)
__global__ void k_gemm_out(const unsigned short* __restrict__ Ah, const unsigned short* __restrict__ Al,
                           const unsigned short* __restrict__ Wh, const unsigned short* __restrict__ Wl,
                           const float* __restrict__ seq_mask, float* __restrict__ out) {
    __shared__ unsigned short ah_t[128 * 32], al_t[128 * 32], bh_t[128 * 32], bl_t[128 * 32];
    int tid = threadIdx.x, lane = tid & 63, wid = tid >> 6;
    int lc = lane & 15, lq = lane >> 4;
    int wr = wid >> 1, wc = wid & 1;
    int m0 = blockIdx.x * 128, n0 = blockIdx.y * 128;
    f32x4 acc[4][4];
#pragma unroll
    for (int i = 0; i < 4; ++i)
#pragma unroll
        for (int jn = 0; jn < 4; ++jn)
#pragma unroll
            for (int e = 0; e < 4; ++e) acc[i][jn][e] = 0.f;
    int wbase = wid * 64;
    for (int kt = 0; kt < 16; ++kt) {
        __syncthreads();
#pragma unroll
        for (int i = 0; i < 2; ++i) {
            int p = i * 256 + wbase + lane;
            int row = p >> 2, ls = (p & 3) ^ (row & 3);
            size_t asrc = (size_t)(m0 + row) * 512 + kt * 32 + ls * 8;
            size_t bsrc = (size_t)(n0 + row) * 512 + kt * 32 + ls * 8;
            int dst = (i * 256 + wbase) * 8;
            gl_lds16(Ah + asrc, ah_t + dst);
            gl_lds16(Al + asrc, al_t + dst);
            gl_lds16(Wh + bsrc, bh_t + dst);
            gl_lds16(Wl + bsrc, bl_t + dst);
        }
        __syncthreads();
        s16x8 fah[4], fal[4], fbh[4], fbl[4];
#pragma unroll
        for (int mf = 0; mf < 4; ++mf) {
            int row = wr * 64 + mf * 16 + lc;
            int off = row * 64 + ((lq * 16) ^ ((row & 3) << 4));
            fah[mf] = *(const s16x8*)((const char*)ah_t + off);
            fal[mf] = *(const s16x8*)((const char*)al_t + off);
        }
#pragma unroll
        for (int nf = 0; nf < 4; ++nf) {
            int row = wc * 64 + nf * 16 + lc;
            int off = row * 64 + ((lq * 16) ^ ((row & 3) << 4));
            fbh[nf] = *(const s16x8*)((const char*)bh_t + off);
            fbl[nf] = *(const s16x8*)((const char*)bl_t + off);
        }
#pragma unroll
        for (int mf = 0; mf < 4; ++mf)
#pragma unroll
            for (int nf = 0; nf < 4; ++nf) {
                acc[mf][nf] = mfma_bf16(fah[mf], fbh[nf], acc[mf][nf]);
                acc[mf][nf] = mfma_bf16(fah[mf], fbl[nf], acc[mf][nf]);
                acc[mf][nf] = mfma_bf16(fal[mf], fbh[nf], acc[mf][nf]);
            }
    }
#pragma unroll
    for (int mf = 0; mf < 4; ++mf)
#pragma unroll
        for (int nf = 0; nf < 4; ++nf)
#pragma unroll
            for (int r = 0; r < 4; ++r) {
                int grow = m0 + wr * 64 + mf * 16 + lq * 4 + r;
                int gcol = n0 + wc * 64 + nf * 16 + lc;
                out[(size_t)grow * 512 + gcol] = acc[mf][nf][r] * seq_mask[grow];
            }
}

// ---------------------------------------------------------------------------
extern "C" void kernel_launch(void* const* d_in, const int* in_sizes, int n_in,
                              void* d_out, int out_size, void* d_ws, size_t ws_size,
                              hipStream_t stream) {
    const float* x         = (const float*)d_in[0];
    const float* timev     = (const float*)d_in[1];
    const float* attn_bias = (const float*)d_in[2];
    const float* seq_mask  = (const float*)d_in[3];
    const float* gamma     = (const float*)d_in[4];
    const float* w_time    = (const float*)d_in[5];
    const float* b_time    = (const float*)d_in[6];
    const float* w_q       = (const float*)d_in[7];
    const float* w_kv      = (const float*)d_in[8];
    const float* w_out     = (const float*)d_in[9];
    float* out = (float*)d_out;

    char* ws = (char*)d_ws;
    size_t off = 0;
    auto alloc = [&](size_t bytes) {
        char* p = ws + off;
        off += (bytes + 255) & ~(size_t)255;
        return p;
    };
    float*          tc   = (float*)alloc(2048 * 4);
    unsigned short* wq   = (unsigned short*)alloc(262144 * 2);
    unsigned short* wkv  = (unsigned short*)alloc(524288 * 2);
    unsigned short* wo_h = (unsigned short*)alloc(262144 * 2);
    unsigned short* wo_l = (unsigned short*)alloc(262144 * 2);
    unsigned short* xbf  = (unsigned short*)alloc(2097152 * 2);
    unsigned short* xnbf = (unsigned short*)alloc(2097152 * 2);
    unsigned short* qb   = (unsigned short*)alloc(2097152 * 2);
    unsigned short* kb   = (unsigned short*)alloc(2097152 * 2);
    unsigned short* vtb  = (unsigned short*)alloc(2097152 * 2);
    unsigned short* ahh  = (unsigned short*)alloc(2097152 * 2);
    unsigned short* all_ = (unsigned short*)alloc(2097152 * 2);
    float*          po   = (float*)alloc((size_t)2 * 16 * 2048 * 64 * 4);  // 16.8MB
    float*          ml   = (float*)alloc((size_t)2 * 16 * 2048 * 2 * 4);   // 0.5MB

    k_prep<<<4096, 256, 0, stream>>>(w_q, w_kv, w_out, wq, wkv, wo_h, wo_l);
    k_time<<<512, 256, 0, stream>>>(timev, w_time, b_time, tc);
    k_lnfilm<<<4096, 256, 0, stream>>>(x, gamma, seq_mask, tc, xbf, xnbf);
    k_gemm<0><<<dim3(32, 4), 256, 0, stream>>>(xnbf, wq, qb, nullptr);
    k_gemm<1><<<dim3(32, 8), 256, 0, stream>>>(xbf, wkv, kb, vtb);
    k_attn<<<1024, 256, 0, stream>>>(qb, kb, vtb, attn_bias, seq_mask, po, ml);
    k_comb<<<512, 256, 0, stream>>>(po, ml, ahh, all_);
    k_gemm_out<<<dim3(32, 4), 256, 0, stream>>>(ahh, all_, wo_h, wo_l, seq_mask, out);
}

// Round 7
// 159.888 us; speedup vs baseline: 1.6719x; 1.6719x over previous
//
#include <hip/hip_runtime.h>
#include <stdint.h>

// ---------------------------------------------------------------------------
// TimeCondAttention on MI355X (gfx950)
// B=2, N=2048, DIM=512, H=8, DH=64, TIME_DIM=512
// R7: R3/R4 pipeline shape + 4 blocks/CU:
//   - key-split x2 (grid 1024), k_comb merges halves (verified R6)
//   - K/V gl_lds rings depth 2 (40KB LDS) -> 4 blocks/CU, 16 waves/CU
//   - bias reg ping-pong, issued mid-iter after current tile consumed
//   - tail s_waitcnt vmcnt(4) lgkmcnt(0) + s_barrier (bias flies across)
//   - target VGPR <= 128 under __launch_bounds__(256,4)
// ---------------------------------------------------------------------------

using s16x8 = __attribute__((ext_vector_type(8))) short;
using f32x4 = __attribute__((ext_vector_type(4))) float;
using u16x4 = __attribute__((ext_vector_type(4))) unsigned short;

#define EPSV 1e-5f
#define NEGV 1e6f

__device__ __forceinline__ unsigned short f2bf(float f) {
    unsigned int u = __float_as_uint(f);
    u += 0x7FFFu + ((u >> 16) & 1u);   // RNE (inputs finite)
    return (unsigned short)(u >> 16);
}
__device__ __forceinline__ float bf2f(unsigned short s) {
    return __uint_as_float((unsigned int)s << 16);
}

__device__ __forceinline__ void gl_lds16(const void* g, void* l) {
    __builtin_amdgcn_global_load_lds((const __attribute__((address_space(1))) void*)g,
                                     (__attribute__((address_space(3))) void*)l, 16, 0, 0);
}

__device__ __forceinline__ f32x4 mfma_bf16(s16x8 a, s16x8 b, f32x4 c) {
    return __builtin_amdgcn_mfma_f32_16x16x32_bf16(a, b, c, 0, 0, 0);
}

// ---------------- K0: weight conversion (w_q, w_kv bf16; w_out hi/lo split) --
__global__ void k_prep(const float* __restrict__ w_q, const float* __restrict__ w_kv,
                       const float* __restrict__ w_out,
                       unsigned short* __restrict__ wq, unsigned short* __restrict__ wkv,
                       unsigned short* __restrict__ wo_h, unsigned short* __restrict__ wo_l) {
    int idx = blockIdx.x * 256 + threadIdx.x;         // total 1,048,576 exactly
    if (idx < 262144) {
        wq[idx] = f2bf(w_q[idx]);
    } else if (idx < 786432) {
        int i = idx - 262144;
        wkv[i] = f2bf(w_kv[i]);
    } else {
        int i = idx - 786432;
        float v = w_out[i];
        unsigned short h = f2bf(v);
        wo_h[i] = h;
        wo_l[i] = f2bf(v - bf2f(h));
    }
}

// ---------------- K1: t = silu(time) @ w_time.T + b_time  ([2][1024] f32) ----
__global__ void k_time(const float* __restrict__ timev, const float* __restrict__ w_time,
                       const float* __restrict__ b_time, float* __restrict__ tc) {
    int wid = threadIdx.x >> 6, lane = threadIdx.x & 63;
    int b = blockIdx.x >> 8;
    int j = (blockIdx.x & 255) * 4 + wid;             // 0..1023
    const float* tv = timev + b * 512;
    const float* wr = w_time + (size_t)j * 512;
    float acc = 0.f;
#pragma unroll
    for (int i = 0; i < 8; ++i) {
        int k = i * 64 + lane;
        float t = tv[k];
        float s = t / (1.f + __expf(-t));             // silu
        acc += s * wr[k];
    }
#pragma unroll
    for (int m = 32; m >= 1; m >>= 1) acc += __shfl_xor(acc, m);
    if (lane == 0) tc[b * 1024 + j] = acc + b_time[j];
}

// ---------------- K2: LayerNorm + FiLM + seq_mask -> xn(bf16); x -> bf16 -----
__global__ void k_lnfilm(const float* __restrict__ x, const float* __restrict__ gamma,
                         const float* __restrict__ seq_mask, const float* __restrict__ tc,
                         unsigned short* __restrict__ xbf, unsigned short* __restrict__ xnbf) {
    int row = blockIdx.x;                             // b*2048 + n
    int b = row >> 11;
    int tid = threadIdx.x, wid = tid >> 6, lane = tid & 63;
    float2 xv = *(const float2*)(x + (size_t)row * 512 + tid * 2);
    float s = xv.x + xv.y;
    float sq = xv.x * xv.x + xv.y * xv.y;
#pragma unroll
    for (int m = 32; m >= 1; m >>= 1) { s += __shfl_xor(s, m); sq += __shfl_xor(sq, m); }
    __shared__ float red[8];
    if (lane == 0) { red[wid] = s; red[wid + 4] = sq; }
    __syncthreads();
    float ts = red[0] + red[1] + red[2] + red[3];
    float tq = red[4] + red[5] + red[6] + red[7];
    float mu = ts * (1.f / 512.f);
    float var = tq * (1.f / 512.f) - mu * mu;
    float rs = rsqrtf(var + EPSV);
    float qm = seq_mask[row];
    int j = tid * 2;
    const float* scb = tc + b * 1024;
    float o0 = ((xv.x - mu) * rs * gamma[j])     * (scb[j] + 1.f)     + scb[j + 512];
    float o1 = ((xv.y - mu) * rs * gamma[j + 1]) * (scb[j + 1] + 1.f) + scb[j + 513];
    size_t base = (size_t)row * 512 + j;
    xnbf[base]     = f2bf(o0 * qm);
    xnbf[base + 1] = f2bf(o1 * qm);
    xbf[base]      = f2bf(xv.x);
    xbf[base + 1]  = f2bf(xv.y);
}

// ---------------- K3: bf16 GEMM C = A[M,512] * W[Nout,512]^T, scatter epi ----
// EPI 0: q-proj (scale 0.125, [b,h,n,d]); EPI 1: kv-proj (k: [b,h,n,d], v: [b,h,d,n])
template<int EPI>
__launch_bounds__(256)
__global__ void k_gemm(const unsigned short* __restrict__ A, const unsigned short* __restrict__ W,
                       unsigned short* __restrict__ o0, unsigned short* __restrict__ o1) {
    __shared__ unsigned short a_t[128 * 64];
    __shared__ unsigned short b_t[128 * 64];
    int tid = threadIdx.x, lane = tid & 63, wid = tid >> 6;
    int lc = lane & 15, lq = lane >> 4;
    int wr = wid >> 1, wc = wid & 1;
    int m0 = blockIdx.x * 128, n0 = blockIdx.y * 128;
    f32x4 acc[4][4];
#pragma unroll
    for (int i = 0; i < 4; ++i)
#pragma unroll
        for (int jn = 0; jn < 4; ++jn)
#pragma unroll
            for (int e = 0; e < 4; ++e) acc[i][jn][e] = 0.f;
    const unsigned short* Ab = A + (size_t)m0 * 512;
    const unsigned short* Wb = W + (size_t)n0 * 512;
    int wbase = wid * 64;
    for (int kt = 0; kt < 8; ++kt) {
        __syncthreads();
        // stage 128x64 bf16 tiles; XOR-swizzled source so swizzled reads work
#pragma unroll
        for (int i = 0; i < 4; ++i) {
            int p = i * 256 + wbase + lane;
            int row = p >> 3, ls = (p & 7) ^ (row & 7);
            gl_lds16(Ab + (size_t)row * 512 + kt * 64 + ls * 8, a_t + (i * 256 + wbase) * 8);
            gl_lds16(Wb + (size_t)row * 512 + kt * 64 + ls * 8, b_t + (i * 256 + wbase) * 8);
        }
        __syncthreads();
        s16x8 af[4][2], bw[4][2];
        const char* ab = (const char*)a_t;
        const char* bb = (const char*)b_t;
#pragma unroll
        for (int mf = 0; mf < 4; ++mf) {
            int row = wr * 64 + mf * 16 + lc;
            int key = (row & 7) << 4;
            af[mf][0] = *(const s16x8*)(ab + row * 128 + ((lq * 16) ^ key));
            af[mf][1] = *(const s16x8*)(ab + row * 128 + ((64 + lq * 16) ^ key));
        }
#pragma unroll
        for (int nf = 0; nf < 4; ++nf) {
            int row = wc * 64 + nf * 16 + lc;
            int key = (row & 7) << 4;
            bw[nf][0] = *(const s16x8*)(bb + row * 128 + ((lq * 16) ^ key));
            bw[nf][1] = *(const s16x8*)(bb + row * 128 + ((64 + lq * 16) ^ key));
        }
#pragma unroll
        for (int mf = 0; mf < 4; ++mf)
#pragma unroll
            for (int nf = 0; nf < 4; ++nf) {
                acc[mf][nf] = mfma_bf16(af[mf][0], bw[nf][0], acc[mf][nf]);
                acc[mf][nf] = mfma_bf16(af[mf][1], bw[nf][1], acc[mf][nf]);
            }
    }
#pragma unroll
    for (int mf = 0; mf < 4; ++mf)
#pragma unroll
        for (int nf = 0; nf < 4; ++nf) {
            int grow0 = m0 + wr * 64 + mf * 16 + lq * 4;
            int gcol = n0 + wc * 64 + nf * 16 + lc;
            int b = grow0 >> 11, nb = grow0 & 2047;
            if (EPI == 0) {
                int h = gcol >> 6, d = gcol & 63;
#pragma unroll
                for (int r = 0; r < 4; ++r)
                    o0[((size_t)((b * 8 + h) * 2048 + nb + r)) * 64 + d] =
                        f2bf(acc[mf][nf][r] * 0.125f);
            } else if (gcol < 512) {
                int h = gcol >> 6, d = gcol & 63;
#pragma unroll
                for (int r = 0; r < 4; ++r)
                    o0[((size_t)((b * 8 + h) * 2048 + nb + r)) * 64 + d] = f2bf(acc[mf][nf][r]);
            } else {
                int jj = gcol & 511;
                int h = jj >> 6, d = jj & 63;
                u16x4 vv;
#pragma unroll
                for (int r = 0; r < 4; ++r) vv[r] = f2bf(acc[mf][nf][r]);
                // V stored transposed [b,h,d,n]; 4 consecutive n -> 8B store
                *(u16x4*)(o1 + ((size_t)((b * 8 + h) * 64 + d)) * 2048 + nb) = vv;
            }
        }
}

// ---------------- K4: flash attention, key-split, 4 blocks/CU ---------------
__launch_bounds__(256, 4)
__global__ void k_attn(const unsigned short* __restrict__ qg, const unsigned short* __restrict__ kg,
                       const unsigned short* __restrict__ vt, const float* __restrict__ bias,
                       const float* __restrict__ seq_mask,
                       float* __restrict__ po, float* __restrict__ ml) {
    __shared__ unsigned short k_ring[2][64 * 64];   // [key][d] swizzled, 8KB/slot
    __shared__ unsigned short v_ring[2][64 * 64];   // [d][key] swizzled, 8KB/slot
    __shared__ unsigned short p_lds[4][16 * 64];    // per-wave P, 2KB/wave

    int tid = threadIdx.x, lane = tid & 63, w = tid >> 6;
    int lc = lane & 15, lq = lane >> 4;

    // XCD mapping: 1024 blocks; XCD c hosts bh {2c,2c+1} (K/V L2-resident)
    int lin = blockIdx.x;
    int vid = (lin & 7) * 128 + (lin >> 3);
    int bh = vid >> 6;
    int rem = vid & 63;
    int half = rem >> 5;
    int q0 = (rem & 31) * 64 + w * 16;
    int b = bh >> 3;

    // Q fragments (B-operand of swapped mfma)
    const unsigned short* qbase = qg + ((size_t)bh * 2048 + q0) * 64;
    s16x8 aq0 = *(const s16x8*)(qbase + lc * 64 + lq * 8);
    s16x8 aq1 = *(const s16x8*)(qbase + lc * 64 + 32 + lq * 8);

    const unsigned short* kb = kg + ((size_t)bh * 2048 + half * 1024) * 64;
    const unsigned short* vt0 = vt + (size_t)bh * 64 * 2048;
    const float* bq = bias + ((size_t)bh * 2048 + q0 + lc) * 2048 + half * 1024;
    const float* sk = seq_mask + b * 2048 + half * 1024;
    float qm = seq_mask[b * 2048 + q0 + lc];

    char* pw = (char*)(&p_lds[w][0]);
    int swz = (lc & 7) << 4;

    float mst = -1e30f, lst = 0.f;
    f32x4 acc[4];
#pragma unroll
    for (int df = 0; df < 4; ++df)
#pragma unroll
        for (int e = 0; e < 4; ++e) acc[df][e] = 0.f;

    auto issue_k = [&](int tile, int slot) {
#pragma unroll
        for (int i = 0; i < 2; ++i) {
            int off = w * 2048 + i * 1024 + lane * 16;
            int row = off >> 7;
            int cc = ((off >> 4) & 7) ^ (row & 7);
            gl_lds16(kb + ((size_t)tile * 64 + row) * 64 + cc * 8,
                     (char*)k_ring[slot] + w * 2048 + i * 1024);
        }
    };
    auto issue_vt = [&](int tile, int slot) {
#pragma unroll
        for (int i = 0; i < 2; ++i) {
            int off = w * 2048 + i * 1024 + lane * 16;
            int row = off >> 7;
            int cc = ((off >> 4) & 7) ^ (row & 7);
            gl_lds16(vt0 + (size_t)row * 2048 + half * 1024 + tile * 64 + cc * 8,
                     (char*)v_ring[slot] + w * 2048 + i * 1024);
        }
    };

    f32x4 brA[4], brB[4];

    // ---- prologue: KV(0)->slot0; bias(0)->brA; wait KV; barrier ----
    issue_k(0, 0);
    issue_vt(0, 0);
    __builtin_amdgcn_sched_barrier(0);
#pragma unroll
    for (int nf = 0; nf < 4; ++nf)
        brA[nf] = *(const f32x4*)(bq + nf * 16 + lq * 4);
    __builtin_amdgcn_sched_barrier(0);
    asm volatile("s_waitcnt vmcnt(4)");
    __builtin_amdgcn_s_barrier();
    __builtin_amdgcn_sched_barrier(0);

    auto iter = [&](int kt, int par, f32x4 (&cur)[4], f32x4 (&nxt)[4]) {
        const int slot_nxt = par ^ 1;

        // ---- S^T = K Q^T from LDS slot par ----
        const char* klds = (const char*)k_ring[par];
        f32x4 sv[4];
        __builtin_amdgcn_s_setprio(1);
#pragma unroll
        for (int nf = 0; nf < 4; ++nf) {
            int row = nf * 16 + lc;
            s16x8 b0 = *(const s16x8*)(klds + row * 128 + ((lq * 16) ^ swz));
            s16x8 b1 = *(const s16x8*)(klds + row * 128 + ((64 + lq * 16) ^ swz));
            f32x4 z;
            z[0] = 0.f; z[1] = 0.f; z[2] = 0.f; z[3] = 0.f;
            z = mfma_bf16(b0, aq0, z);
            z = mfma_bf16(b1, aq1, z);
            sv[nf] = z;
        }
        __builtin_amdgcn_s_setprio(0);

        // ---- bias add (consumes cur) + key mask ----
#pragma unroll
        for (int nf = 0; nf < 4; ++nf) {
            f32x4 km = *(const f32x4*)(sk + kt * 64 + nf * 16 + lq * 4);
            sv[nf] = sv[nf] + cur[nf] + (km * qm - 1.f) * NEGV;
        }
        __builtin_amdgcn_sched_barrier(0);

        // ---- prefetch KV(kt+1) -> slot nxt; bias(kt+1) -> nxt regs ----
        {
            int tk = (kt + 1 < 16) ? kt + 1 : 15;
            issue_k(tk, slot_nxt);
            issue_vt(tk, slot_nxt);
#pragma unroll
            for (int nf = 0; nf < 4; ++nf)
                nxt[nf] = *(const f32x4*)(bq + (size_t)tk * 64 + nf * 16 + lq * 4);
        }
        __builtin_amdgcn_sched_barrier(0);

        // ---- online softmax (row = q = lc; 2 shfl per reduce) ----
        f32x4 m4 = sv[0];
#pragma unroll
        for (int nf = 1; nf < 4; ++nf)
#pragma unroll
            for (int e = 0; e < 4; ++e) m4[e] = fmaxf(m4[e], sv[nf][e]);
        float mx = fmaxf(fmaxf(m4[0], m4[1]), fmaxf(m4[2], m4[3]));
        mx = fmaxf(mx, __shfl_xor(mx, 16));
        mx = fmaxf(mx, __shfl_xor(mx, 32));
        float mn = fmaxf(mst, mx);
        float scl = __expf(mst - mn);
        mst = mn;
        float rsum = 0.f;
#pragma unroll
        for (int nf = 0; nf < 4; ++nf) {
            f32x4 p;
#pragma unroll
            for (int e = 0; e < 4; ++e) { p[e] = __expf(sv[nf][e] - mn); rsum += p[e]; }
            unsigned int w0 = ((unsigned)f2bf(p[1]) << 16) | f2bf(p[0]);
            unsigned int w1 = ((unsigned)f2bf(p[3]) << 16) | f2bf(p[2]);
            *(unsigned int*)(pw + lc * 128 + ((nf * 32 + lq * 8) ^ swz)) = w0;
            *(unsigned int*)(pw + lc * 128 + ((nf * 32 + lq * 8 + 4) ^ swz)) = w1;
        }
        rsum += __shfl_xor(rsum, 16);
        rsum += __shfl_xor(rsum, 32);
        lst = lst * scl + rsum;
#pragma unroll
        for (int df = 0; df < 4; ++df)
#pragma unroll
            for (int e = 0; e < 4; ++e) acc[df][e] *= scl;

        __builtin_amdgcn_sched_barrier(0);
        asm volatile("s_waitcnt lgkmcnt(0)");   // P visible (wave-local)
        __builtin_amdgcn_sched_barrier(0);      // rule #18

        // ---- O^T += V^T P^T from LDS slot par ----
        s16x8 ap0 = *(const s16x8*)(pw + lc * 128 + ((lq * 16) ^ swz));
        s16x8 ap1 = *(const s16x8*)(pw + lc * 128 + ((64 + lq * 16) ^ swz));
        const char* vlds = (const char*)v_ring[par];
        __builtin_amdgcn_s_setprio(1);
#pragma unroll
        for (int df = 0; df < 4; ++df) {
            int row = df * 16 + lc;
            int key = (row & 7) << 4;
            s16x8 av0 = *(const s16x8*)(vlds + row * 128 + ((lq * 16) ^ key));
            s16x8 av1 = *(const s16x8*)(vlds + row * 128 + ((64 + lq * 16) ^ key));
            acc[df] = mfma_bf16(av0, ap0, acc[df]);
            acc[df] = mfma_bf16(av1, ap1, acc[df]);
        }
        __builtin_amdgcn_s_setprio(0);

        // ---- tail: KV(kt+1) landed; bias(kt+1) (newest 4) flies on ----
        __builtin_amdgcn_sched_barrier(0);
        asm volatile("s_waitcnt vmcnt(4) lgkmcnt(0)");
        __builtin_amdgcn_s_barrier();
        __builtin_amdgcn_sched_barrier(0);
    };

    for (int t = 0; t < 8; ++t) {
        iter(2 * t,     0, brA, brB);
        iter(2 * t + 1, 1, brB, brA);
    }
    asm volatile("s_waitcnt vmcnt(0)");   // retire dangling clamped prefetches

    // ---- partial output (unnormalized acc + m, l) ----
    float* prow = po + ((size_t)((half * 16 + bh) * 2048) + q0 + lc) * 64;
#pragma unroll
    for (int df = 0; df < 4; ++df)
        *(f32x4*)(prow + df * 16 + lq * 4) = acc[df];
    if (lq == 0) {
        int r = (half * 16 + bh) * 2048 + q0 + lc;
        ml[2 * r] = mst;
        ml[2 * r + 1] = lst;
    }
}

// ---------------- K4b: merge key-halves -> ah/al (hi/lo bf16 split) ---------
__global__ void k_comb(const float* __restrict__ po, const float* __restrict__ ml,
                       unsigned short* __restrict__ ah, unsigned short* __restrict__ al) {
    int g = blockIdx.x * 256 + threadIdx.x;   // 131072 = 32768 rows x 4 chunks
    int row = g >> 2, ch = g & 3;
    int bh = row >> 11, q = row & 2047;
    int b = bh >> 3, h = bh & 7;
    float m0 = ml[2 * row],           l0 = ml[2 * row + 1];
    float m1 = ml[2 * (row + 32768)], l1 = ml[2 * (row + 32768) + 1];
    float m = fmaxf(m0, m1);
    float e0 = __expf(m0 - m), e1 = __expf(m1 - m);
    float inv = 1.f / (e0 * l0 + e1 * l1);
    const float* p0 = po + (size_t)row * 64 + ch * 16;
    const float* p1 = p0 + (size_t)32768 * 64;
    size_t ob = ((size_t)(b * 2048 + q)) * 512 + h * 64 + ch * 16;
#pragma unroll
    for (int i = 0; i < 4; ++i) {
        f32x4 a0 = *(const f32x4*)(p0 + i * 4);
        f32x4 a1 = *(const f32x4*)(p1 + i * 4);
        u16x4 hi, lo;
#pragma unroll
        for (int e = 0; e < 4; ++e) {
            float o = (e0 * a0[e] + e1 * a1[e]) * inv;
            unsigned short hb = f2bf(o);
            hi[e] = hb;
            lo[e] = f2bf(o - bf2f(hb));
        }
        *(u16x4*)(ah + ob + i * 4) = hi;
        *(u16x4*)(al + ob + i * 4) = lo;
    }
}

// ---------------- K5: out = (Ah+Al)(Wh+Wl)^T * seq_mask  (3-term split) -----
__launch_bounds__(256)
__global__ void k_gemm_out(const unsigned short* __restrict__ Ah, const unsigned short* __restrict__ Al,
                           const unsigned short* __restrict__ Wh, const unsigned short* __restrict__ Wl,
                           const float* __restrict__ seq_mask, float* __restrict__ out) {
    __shared__ unsigned short ah_t[128 * 32], al_t[128 * 32], bh_t[128 * 32], bl_t[128 * 32];
    int tid = threadIdx.x, lane = tid & 63, wid = tid >> 6;
    int lc = lane & 15, lq = lane >> 4;
    int wr = wid >> 1, wc = wid & 1;
    int m0 = blockIdx.x * 128, n0 = blockIdx.y * 128;
    f32x4 acc[4][4];
#pragma unroll
    for (int i = 0; i < 4; ++i)
#pragma unroll
        for (int jn = 0; jn < 4; ++jn)
#pragma unroll
            for (int e = 0; e < 4; ++e) acc[i][jn][e] = 0.f;
    int wbase = wid * 64;
    for (int kt = 0; kt < 16; ++kt) {
        __syncthreads();
#pragma unroll
        for (int i = 0; i < 2; ++i) {
            int p = i * 256 + wbase + lane;
            int row = p >> 2, ls = (p & 3) ^ (row & 3);
            size_t asrc = (size_t)(m0 + row) * 512 + kt * 32 + ls * 8;
            size_t bsrc = (size_t)(n0 + row) * 512 + kt * 32 + ls * 8;
            int dst = (i * 256 + wbase) * 8;
            gl_lds16(Ah + asrc, ah_t + dst);
            gl_lds16(Al + asrc, al_t + dst);
            gl_lds16(Wh + bsrc, bh_t + dst);
            gl_lds16(Wl + bsrc, bl_t + dst);
        }
        __syncthreads();
        s16x8 fah[4], fal[4], fbh[4], fbl[4];
#pragma unroll
        for (int mf = 0; mf < 4; ++mf) {
            int row = wr * 64 + mf * 16 + lc;
            int off = row * 64 + ((lq * 16) ^ ((row & 3) << 4));
            fah[mf] = *(const s16x8*)((const char*)ah_t + off);
            fal[mf] = *(const s16x8*)((const char*)al_t + off);
        }
#pragma unroll
        for (int nf = 0; nf < 4; ++nf) {
            int row = wc * 64 + nf * 16 + lc;
            int off = row * 64 + ((lq * 16) ^ ((row & 3) << 4));
            fbh[nf] = *(const s16x8*)((const char*)bh_t + off);
            fbl[nf] = *(const s16x8*)((const char*)bl_t + off);
        }
#pragma unroll
        for (int mf = 0; mf < 4; ++mf)
#pragma unroll
            for (int nf = 0; nf < 4; ++nf) {
                acc[mf][nf] = mfma_bf16(fah[mf], fbh[nf], acc[mf][nf]);
                acc[mf][nf] = mfma_bf16(fah[mf], fbl[nf], acc[mf][nf]);
                acc[mf][nf] = mfma_bf16(fal[mf], fbh[nf], acc[mf][nf]);
            }
    }
#pragma unroll
    for (int mf = 0; mf < 4; ++mf)
#pragma unroll
        for (int nf = 0; nf < 4; ++nf)
#pragma unroll
            for (int r = 0; r < 4; ++r) {
                int grow = m0 + wr * 64 + mf * 16 + lq * 4 + r;
                int gcol = n0 + wc * 64 + nf * 16 + lc;
                out[(size_t)grow * 512 + gcol] = acc[mf][nf][r] * seq_mask[grow];
            }
}

// ---------------------------------------------------------------------------
extern "C" void kernel_launch(void* const* d_in, const int* in_sizes, int n_in,
                              void* d_out, int out_size, void* d_ws, size_t ws_size,
                              hipStream_t stream) {
    const float* x         = (const float*)d_in[0];
    const float* timev     = (const float*)d_in[1];
    const float* attn_bias = (const float*)d_in[2];
    const float* seq_mask  = (const float*)d_in[3];
    const float* gamma     = (const float*)d_in[4];
    const float* w_time    = (const float*)d_in[5];
    const float* b_time    = (const float*)d_in[6];
    const float* w_q       = (const float*)d_in[7];
    const float* w_kv      = (const float*)d_in[8];
    const float* w_out     = (const float*)d_in[9];
    float* out = (float*)d_out;

    char* ws = (char*)d_ws;
    size_t off = 0;
    auto alloc = [&](size_t bytes) {
        char* p = ws + off;
        off += (bytes + 255) & ~(size_t)255;
        return p;
    };
    float*          tc   = (float*)alloc(2048 * 4);
    unsigned short* wq   = (unsigned short*)alloc(262144 * 2);
    unsigned short* wkv  = (unsigned short*)alloc(524288 * 2);
    unsigned short* wo_h = (unsigned short*)alloc(262144 * 2);
    unsigned short* wo_l = (unsigned short*)alloc(262144 * 2);
    unsigned short* xbf  = (unsigned short*)alloc(2097152 * 2);
    unsigned short* xnbf = (unsigned short*)alloc(2097152 * 2);
    unsigned short* qb   = (unsigned short*)alloc(2097152 * 2);
    unsigned short* kb   = (unsigned short*)alloc(2097152 * 2);
    unsigned short* vtb  = (unsigned short*)alloc(2097152 * 2);
    unsigned short* ahh  = (unsigned short*)alloc(2097152 * 2);
    unsigned short* all_ = (unsigned short*)alloc(2097152 * 2);
    float*          po   = (float*)alloc((size_t)2 * 16 * 2048 * 64 * 4);  // 16.8MB
    float*          ml   = (float*)alloc((size_t)2 * 16 * 2048 * 2 * 4);   // 0.5MB

    k_prep<<<4096, 256, 0, stream>>>(w_q, w_kv, w_out, wq, wkv, wo_h, wo_l);
    k_time<<<512, 256, 0, stream>>>(timev, w_time, b_time, tc);
    k_lnfilm<<<4096, 256, 0, stream>>>(x, gamma, seq_mask, tc, xbf, xnbf);
    k_gemm<0><<<dim3(32, 4), 256, 0, stream>>>(xnbf, wq, qb, nullptr);
    k_gemm<1><<<dim3(32, 8), 256, 0, stream>>>(xbf, wkv, kb, vtb);
    k_attn<<<1024, 256, 0, stream>>>(qb, kb, vtb, attn_bias, seq_mask, po, ml);
    k_comb<<<512, 256, 0, stream>>>(po, ml, ahh, all_);
    k_gemm_out<<<dim3(32, 4), 256, 0, stream>>>(ahh, all_, wo_h, wo_l, seq_mask, out);
}